// Round 6
// baseline (341.280 us; speedup 1.0000x reference)
//
#include <hip/hip_runtime.h>
#include <hip/hip_bf16.h>

typedef __bf16 bf16x8 __attribute__((ext_vector_type(8)));
typedef __bf16 bf16x4 __attribute__((ext_vector_type(4)));
typedef float  f32x4  __attribute__((ext_vector_type(4)));

#define MFMA16(a, b, c) __builtin_amdgcn_mfma_f32_16x16x32_bf16((a), (b), (c), 0, 0, 0)

// ---------------------------------------------------------------------------
// K1: block 240: exclusive scan of sizes; blocks 0-47: conv weight pack;
// blocks 48-239: lin_w hi/lo pack.
// B-frag for 16x16x32: lane holds B[k = (lane>>4)*8 + j][n = lane&15], j=0..7.
// ---------------------------------------------------------------------------
__global__ void k_prep(const int* __restrict__ sizes, int* __restrict__ offsets,
                       const float* __restrict__ w0, const float* __restrict__ w1,
                       const float* __restrict__ w2, const float* __restrict__ lw,
                       __bf16* __restrict__ Wpack,
                       __bf16* __restrict__ Lhi, __bf16* __restrict__ Llo) {
  const int bid = blockIdx.x, t = threadIdx.x;
  if (bid == 240) {
    __shared__ int part[256];
    const int base = t * 32;
    int v[32];
    int s = 0;
#pragma unroll
    for (int i = 0; i < 32; ++i) { v[i] = sizes[base + i]; s += v[i]; }
    part[t] = s;
    __syncthreads();
    for (int d = 1; d < 256; d <<= 1) {
      int add = (t >= d) ? part[t - d] : 0;
      __syncthreads();
      part[t] += add;
      __syncthreads();
    }
    int run = (t == 0) ? 0 : part[t - 1];
#pragma unroll
    for (int i = 0; i < 32; ++i) { offsets[base + i] = run; run += v[i]; }
  } else if (bid < 48) {
    const int nt = bid, sl = nt >> 3, f = nt & 7;
    const int kt = t >> 6, lane = t & 63;
    const float* src; int kw, jj;
    if      (sl == 0) { src = w0; kw = 1; jj = 0; }
    else if (sl == 1) { src = w1; kw = 2; jj = 0; }
    else if (sl == 2) { src = w1; kw = 2; jj = 1; }
    else if (sl == 3) { src = w2; kw = 3; jj = 0; }
    else if (sl == 4) { src = w2; kw = 3; jj = 1; }
    else              { src = w2; kw = 3; jj = 2; }
    const int feat  = f * 16 + (lane & 15);
    const int cbase = kt * 32 + ((lane >> 4) << 3);
    __bf16* dst = Wpack + ((((nt * 4 + kt) << 6) + lane) << 3);
#pragma unroll
    for (int j = 0; j < 8; ++j)
      dst[j] = (__bf16)src[(feat * 128 + cbase + j) * kw + jj];
  } else {
    const int idx = (bid - 48) * 256 + t;          // 0..49151
    const int j = idx & 7, lane = (idx >> 3) & 63, rest = idx >> 9;  // 0..95
    const int kt = rest % 12, nt = rest / 12;
    const int o = nt * 16 + (lane & 15);
    const int q = kt * 32 + ((lane >> 4) << 3) + j;
    const float v = lw[o * 384 + q];
    const __bf16 hi = (__bf16)v;
    Lhi[idx] = hi;
    Llo[idx] = (__bf16)(v - (float)hi);
  }
}

// ---------------------------------------------------------------------------
// K2: fused conv + relu + ragged max.  One 1024-thread block per segment;
// 16 waves, each owning (ft = wid&7, mt-half = wid>>3) -> acc is only 24
// AGPRs, total unified regs <=64 -> 8 waves/SIMD occupancy.
// Tap shifts via LDS A-row offsets (rows zero-padded through MT*16+1).
// Validity masking folded into acc init (-1e30 sentinel rows).
// C/D layout (m89-verified): col = lane&15, row = (lane>>4)*4 + reg.
// ---------------------------------------------------------------------------
__global__ __launch_bounds__(1024, 8)
void k_conv(const float* __restrict__ x, const int* __restrict__ sizes,
            const int* __restrict__ offsets,
            const float* __restrict__ cb0, const float* __restrict__ cb1,
            const float* __restrict__ cb2,
            const bf16x8* __restrict__ Wpack,
            __bf16* __restrict__ Phi, __bf16* __restrict__ Plo) {
  __shared__ __bf16 xh[66 * 136];    // [row][128 + 8 pad] bf16, 17.9 KB
  __shared__ float  part[16 * 48];   // [wid][pool][feat16], 3 KB
  const int b = blockIdx.x;
  const int s = sizes[b];
  const long off = offsets[b];
  const int t = threadIdx.x;
  const int MT = (s + 15) >> 4;     // 1..4

  // ---- two-phase staging: 2 predicated float4 loads per thread ----
  {
    const int quads = s << 5;       // s*128/4 (<= 2016)
    float4 v0, v1;
    const bool p0 = t < quads, p1 = t + 1024 < quads;
    if (p0) {
      const int r = t >> 5, c = (t & 31) << 2;
      v0 = *(const float4*)(x + (off + r) * 128 + c);
    }
    if (p1) {
      const int qi = t + 1024;
      const int r = qi >> 5, c = (qi & 31) << 2;
      v1 = *(const float4*)(x + (off + r) * 128 + c);
    }
    if (p0) {
      const int r = t >> 5, c = (t & 31) << 2;
      bf16x4 h; h[0] = (__bf16)v0.x; h[1] = (__bf16)v0.y;
                h[2] = (__bf16)v0.z; h[3] = (__bf16)v0.w;
      *(bf16x4*)&xh[r * 136 + c] = h;
    }
    if (p1) {
      const int qi = t + 1024;
      const int r = qi >> 5, c = (qi & 31) << 2;
      bf16x4 h; h[0] = (__bf16)v1.x; h[1] = (__bf16)v1.y;
                h[2] = (__bf16)v1.z; h[3] = (__bf16)v1.w;
      *(bf16x4*)&xh[r * 136 + c] = h;
    }
    // zero rows [s, MT*16+2): taps read up to row MT*16+1
    const int zend = MT * 16 + 2;
    const int r = s + (t >> 5), c = (t & 31) << 2;
    if (r < zend)
      *(bf16x4*)&xh[r * 136 + c] =
          bf16x4{(__bf16)0.f, (__bf16)0.f, (__bf16)0.f, (__bf16)0.f};
  }
  __syncthreads();

  const int wid = t >> 6, lane = t & 63;
  const int ft = wid & 7, mh = wid >> 3;
  const int lo16 = lane & 15, g16 = lane >> 4;
  const int mt0 = mh << 1;

  // ---- acc init: 0 on valid rows, -1e30 sentinel elsewhere ----
  f32x4 acc[2][3];
#pragma unroll
  for (int am = 0; am < 2; ++am)
#pragma unroll
    for (int p = 0; p < 3; ++p)
#pragma unroll
      for (int v = 0; v < 4; ++v) {
        const int lrow = (mt0 + am) * 16 + g16 * 4 + v;
        acc[am][p][v] = (lrow < s - p) ? 0.f : -1e30f;
      }

  if (mt0 < MT) {   // uniform per wave
#pragma unroll
    for (int kt = 0; kt < 4; ++kt) {
      // slices: 0=w1j0, 1=w2j0, 2=w2j1, 3=w3j0, 4=w3j1, 5=w3j2
      const int bbase = ((ft * 4 + kt) << 6) + lane;
      const bf16x8 bf0 = Wpack[bbase];
      const bf16x8 bf1 = Wpack[bbase + (8 * 4 << 6)];
      const bf16x8 bf2 = Wpack[bbase + (16 * 4 << 6)];
      const bf16x8 bf3 = Wpack[bbase + (24 * 4 << 6)];
      const bf16x8 bf4 = Wpack[bbase + (32 * 4 << 6)];
      const bf16x8 bf5 = Wpack[bbase + (40 * 4 << 6)];
#pragma unroll
      for (int am = 0; am < 2; ++am) {
        const int mt = mt0 + am;
        if (mt < MT) {   // uniform per wave
          const __bf16* ap = &xh[(mt * 16 + lo16) * 136 + kt * 32 + (g16 << 3)];
          bf16x8 A = *(const bf16x8*)ap;           // row r (tap j=0)
          acc[am][0] = MFMA16(A, bf0, acc[am][0]);
          acc[am][1] = MFMA16(A, bf1, acc[am][1]);
          acc[am][2] = MFMA16(A, bf3, acc[am][2]);
          A = *(const bf16x8*)(ap + 136);          // row r+1 (tap j=1)
          acc[am][1] = MFMA16(A, bf2, acc[am][1]);
          acc[am][2] = MFMA16(A, bf4, acc[am][2]);
          A = *(const bf16x8*)(ap + 272);          // row r+2 (tap j=2)
          acc[am][2] = MFMA16(A, bf5, acc[am][2]);
        }
      }
    }
  }

  // ---- epilogue: unpredicated max (sentinels exclude invalid rows) ----
  float m[3];
#pragma unroll
  for (int p = 0; p < 3; ++p) {
    float mm = acc[0][p][0];
#pragma unroll
    for (int v = 1; v < 4; ++v) mm = fmaxf(mm, acc[0][p][v]);
#pragma unroll
    for (int v = 0; v < 4; ++v) mm = fmaxf(mm, acc[1][p][v]);
    mm = fmaxf(mm, __shfl_xor(mm, 16));
    mm = fmaxf(mm, __shfl_xor(mm, 32));
    m[p] = mm;
  }
  if (g16 == 0) {
    part[wid * 48 + lo16]      = m[0];
    part[wid * 48 + 16 + lo16] = m[1];
    part[wid * 48 + 32 + lo16] = m[2];
  }
  __syncthreads();
  if (mh == 0 && g16 == 0) {
    const int feat = ft * 16 + lo16;
    const float m1 = fmaxf(part[wid * 48 + lo16],      part[(wid + 8) * 48 + lo16]);
    const float m2 = fmaxf(part[wid * 48 + 16 + lo16], part[(wid + 8) * 48 + 16 + lo16]);
    const float m3 = fmaxf(part[wid * 48 + 32 + lo16], part[(wid + 8) * 48 + 32 + lo16]);
    // max(relu(h)) == relu(max(Y)+b): bias row-constant, relu monotone
    const float p1 = fmaxf(m1 + cb0[feat], 0.f);
    const float p2 = fmaxf(m2 + cb1[feat], 0.f);
    const float p3 = fmaxf(m3 + cb2[feat], 0.f);
    const __bf16 h1 = (__bf16)p1, h2 = (__bf16)p2, h3 = (__bf16)p3;
    const long row = (long)b * 384;
    Phi[row + feat]       = h1;
    Plo[row + feat]       = (__bf16)(p1 - (float)h1);
    Phi[row + 128 + feat] = h2;
    Plo[row + 128 + feat] = (__bf16)(p2 - (float)h2);
    Phi[row + 256 + feat] = h3;
    Plo[row + 256 + feat] = (__bf16)(p3 - (float)h3);
  }
}

// ---------------------------------------------------------------------------
// K3: out = tanh(P[8192,384] @ lin_w^T + lin_b), split bf16 MFMA (3 products:
// Ph*Wh + Pl*Wh + Ph*Wl -> ~fp32 accuracy).  512 blocks x 16 batch rows.
// ---------------------------------------------------------------------------
__global__ __launch_bounds__(256, 4)
void k_lin(const __bf16* __restrict__ Phi, const __bf16* __restrict__ Plo,
           const bf16x8* __restrict__ Lhi, const bf16x8* __restrict__ Llo,
           const float* __restrict__ lb, float* __restrict__ out) {
  __shared__ __bf16 ph[16 * 392];   // [row][384 + 8 pad]
  __shared__ __bf16 pl[16 * 392];
  const int blk = blockIdx.x, t = threadIdx.x;
  const long rbase = (long)blk * 16;
#pragma unroll
  for (int i = 0; i < 3; ++i) {
    const int ci = t + (i << 8);
    const int r = ci / 48, cc = ci % 48;
    *(int4*)&ph[r * 392 + (cc << 3)] = *(const int4*)&Phi[(rbase + r) * 384 + (cc << 3)];
    *(int4*)&pl[r * 392 + (cc << 3)] = *(const int4*)&Plo[(rbase + r) * 384 + (cc << 3)];
  }
  __syncthreads();
  const int wid = t >> 6, lane = t & 63;
  const int lo16 = lane & 15, g = lane >> 4;
#pragma unroll
  for (int ni = 0; ni < 2; ++ni) {
    const int nt = wid + (ni << 2);
    f32x4 acc = f32x4{0.f, 0.f, 0.f, 0.f};
#pragma unroll
    for (int kt = 0; kt < 12; ++kt) {
      const bf16x8 bh = Lhi[((nt * 12 + kt) << 6) + lane];
      const bf16x8 bl = Llo[((nt * 12 + kt) << 6) + lane];
      const int aoff = lo16 * 392 + kt * 32 + (g << 3);
      const bf16x8 ah = *(const bf16x8*)&ph[aoff];
      const bf16x8 al = *(const bf16x8*)&pl[aoff];
      acc = MFMA16(ah, bh, acc);
      acc = MFMA16(al, bh, acc);
      acc = MFMA16(ah, bl, acc);
    }
    const int o = nt * 16 + lo16;
    const float bias = lb[o];
#pragma unroll
    for (int v = 0; v < 4; ++v) {
      const int r = g * 4 + v;
      const float val = acc[v] + bias;
      out[(rbase + r) * 128 + o] = 1.f - 2.f / (__expf(2.f * val) + 1.f);
    }
  }
}

// ---------------------------------------------------------------------------
extern "C" void kernel_launch(void* const* d_in, const int* in_sizes, int n_in,
                              void* d_out, int out_size, void* d_ws, size_t ws_size,
                              hipStream_t stream) {
  const float* x   = (const float*)d_in[0];
  const int* sizes = (const int*)d_in[1];
  const float* w0  = (const float*)d_in[2];
  const float* cb0 = (const float*)d_in[3];
  const float* w1  = (const float*)d_in[4];
  const float* cb1 = (const float*)d_in[5];
  const float* w2  = (const float*)d_in[6];
  const float* cb2 = (const float*)d_in[7];
  const float* lw  = (const float*)d_in[8];
  const float* lb  = (const float*)d_in[9];

  char* ws = (char*)d_ws;
  size_t o = 0;
  int*    offsets = (int*)ws;                 o += 32768;
  __bf16* Wpack   = (__bf16*)(ws + o);        o += 196608;     // 48*4*64*8*2
  __bf16* Lhi     = (__bf16*)(ws + o);        o += 98304;      // 8*12*64*8*2
  __bf16* Llo     = (__bf16*)(ws + o);        o += 98304;
  __bf16* Phi     = (__bf16*)(ws + o);        o += 8192L * 384 * 2;
  __bf16* Plo     = (__bf16*)(ws + o);        o += 8192L * 384 * 2;

  k_prep<<<241, 256, 0, stream>>>(sizes, offsets, w0, w1, w2, lw, Wpack, Lhi, Llo);
  k_conv<<<8192, 1024, 0, stream>>>(x, sizes, offsets, cb0, cb1, cb2,
                                    (const bf16x8*)Wpack, Phi, Plo);
  k_lin<<<512, 256, 0, stream>>>(Phi, Plo, (const bf16x8*)Lhi,
                                 (const bf16x8*)Llo, lb, (float*)d_out);
}